// Round 19
// baseline (1686.650 us; speedup 1.0000x reference)
//
#include <hip/hip_runtime.h>

// DynamicDeepSNN r19 — weights go GLOBAL->REGISTER (no wt LDS at all).
// LOCKED SEMANTICS (r12/r13/r16/r17/r18 passed, absmax 0.0 — do not change):
//   * per-output sequential-K fmaf chain, k ascending (no K-split, no MFMA)
//   * LIF: m = ((0.8f*m) + cur) - rst with separate __f*_rn roundings
//   * inputs probed bf16-or-f32 / biases zero-safe probed
//   * output f32: spk_hist (T,B,NO) then m3 (B,NO)
//   * xs staging keeps the tt<tc guard (r15 crash: OOB x read)
// r18 POST-MORTEM (1.36 ms, VALUBusy 38%): LDS unit ~2.5x oversubscribed;
// wt LDS round-trip = ~60% of LDS cycles. But each weight row is consumed by
// exactly ONE thread -> no sharing -> LDS unneeded. r19: weights load
// per-lane global->VGPR (L2-resident, same global traffic staging already
// paid); LDS keeps only truly-shared xs (broadcast) + spk. L2 layer becomes
// barrier-free; xs staged in 64-k slices (barriers /4). 12 waves/CU target.

typedef unsigned short u16;
typedef unsigned int   u32;

#define THR   128
#define TC    16
#define KBX   64     // xs staging slice (k)
#define KW    16     // weight register granularity (k)
#define MAXNH 256
#define MAXNO 4
#define SPAD  260

__device__ __forceinline__ float bf2f(u16 u){ union{u32 i;float f;}c; c.i=((u32)u)<<16; return c.f; }
__device__ __forceinline__ float ldin(const void*p,size_t e,int bf){
    return bf ? bf2f(((const u16*)p)[e]) : ((const float*)p)[e];
}
__device__ __forceinline__ float4 ldin4(const void*p,size_t e,int bf){
    if(bf){ const ushort4 u=*reinterpret_cast<const ushort4*>((const u16*)p+e);
            return float4{bf2f(u.x),bf2f(u.y),bf2f(u.z),bf2f(u.w)}; }
    return *reinterpret_cast<const float4*>((const float*)p+e);
}
// guarded 4-elem weight-row load: row n (valid<NR), k..k+3 (valid<K)
__device__ __forceinline__ float4 ldw4(const void*W,int n,int NR,int K,int k,int bf){
    float4 v={0.f,0.f,0.f,0.f};
    if(n<NR){
        if(k+3<K) v=ldin4(W,(size_t)n*K+k,bf);
        else{
#pragma unroll
            for(int j=0;j<4;++j)
                ((float*)&v)[j]=(k+j<K)?ldin(W,(size_t)n*K+k+j,bf):0.f;
        }
    }
    return v;
}

__global__ __launch_bounds__(THR,3)
void snn_f32(const void* __restrict__ x,
             const void* __restrict__ W1, const void* __restrict__ b1,
             const void* __restrict__ W2, const void* __restrict__ b2,
             const void* __restrict__ W3, const void* __restrict__ b3,
             float* __restrict__ out,
             int T,int B,int NI,int NH,int NO)
{
    __shared__ __align__(16) float xs[TC][KBX];       // 4 KB
    __shared__ __align__(16) float spk[TC][SPAD];     // 16.64 KB (s1 then s2)
    __shared__ __align__(16) float w3s[MAXNO][SPAD];  // 4.16 KB (probe red reuses)
    __shared__ float d3[TC][MAXNO];                   // 256 B
    __shared__ int   flg[8];

    const int tid=threadIdx.x, gr=blockIdx.x;         // block owns batch row gr
    int* red=(int*)&w3s[0][0];                        // probe scratch (pre-w3s)

    // ---- per-tensor dtype probes (logic identical to r12..r18) ----
    {
        const u16* ptab[7]={(const u16*)x,(const u16*)W1,(const u16*)W2,
                            (const u16*)W3,(const u16*)b1,(const u16*)b2,(const u16*)b3};
        int ntab[7];
        ntab[0]=1024; ntab[1]=1024; ntab[2]=1024;
        ntab[3]=(NO*NH>=512)?512:NO*NH;
        ntab[4]=(NH<256)?NH:256; ntab[5]=ntab[4];
        ntab[6]=(NO<MAXNO)?NO:MAXNO;
        for(int ti=0;ti<7;++ti){
            const u16* p=ptab[ti]; const int n=ntab[ti];
            int cnt=0,nz=0;
            for(int i=tid;i<n;i+=THR){ u16 v=p[i]; if(v)++nz;
                float a=fabsf(bf2f(v)); if(a>1e-3f&&a<64.f)++cnt; }
            red[tid]=cnt; __syncthreads();
            for(int s=THR/2;s>0;s>>=1){ if(tid<s) red[tid]+=red[tid+s]; __syncthreads(); }
            int ca=red[0]; __syncthreads();
            red[tid]=nz; __syncthreads();
            for(int s=THR/2;s>0;s>>=1){ if(tid<s) red[tid]+=red[tid+s]; __syncthreads(); }
            if(tid==0){ int na=red[0]; flg[ti]=(na==0)?-1:((ca*5>n*4)?1:0); }
            __syncthreads();
        }
    }
    const int fx =__builtin_amdgcn_readfirstlane(flg[0]==1);
    const int fw1=__builtin_amdgcn_readfirstlane(flg[1]==1);
    const int fw2=__builtin_amdgcn_readfirstlane(flg[2]==1);
    const int fw3=__builtin_amdgcn_readfirstlane(flg[3]==1);

    // this thread's two neurons
    const int n0=tid, n1=tid+THR;

    float bb1[2]={0.f,0.f}, bb2[2]={0.f,0.f};
#pragma unroll
    for(int jj=0;jj<2;++jj){
        const int n=tid+THR*jj;
        if(n<NH){ if(flg[4]>=0) bb1[jj]=ldin(b1,(size_t)n,flg[4]==1);
                  if(flg[5]>=0) bb2[jj]=ldin(b2,(size_t)n,flg[5]==1); }
    }
    float bb3v=0.f;
    if(tid<NO && flg[6]>=0) bb3v=ldin(b3,(size_t)tid,flg[6]==1);
    __syncthreads();   // probes done before w3s overwrites red

    // stage W3 once; zero spike buffer (pad cols stay 0 forever)
    for(int e=tid;e<MAXNO*MAXNH;e+=THR){
        int o=e>>8,k=e&255;
        w3s[o][k]=(o<NO&&k<NH)? ldin(W3,(size_t)o*NH+k,fw3):0.f;
    }
    for(int e=tid;e<TC*SPAD;e+=THR) (&spk[0][0])[e]=0.f;
    __syncthreads();

    float m1[2]={0.f,0.f}, m2[2]={0.f,0.f}, m3r=0.f;
    float acc[TC][2];
    float wr0[KW], wr1[KW];

    for(int t0=0;t0<T;t0+=TC){
        const int tc=(T-t0<TC)?(T-t0):TC;

        // ================= layer 1: cur1 = x @ W1^T (sequential k) =========
#pragma unroll
        for(int tt=0;tt<TC;++tt){ acc[tt][0]=0.f; acc[tt][1]=0.f; }

        for(int kb=0;kb<NI;kb+=KBX){
            // stage xs slice kb..kb+63: TC*(KBX/4)=256 quads, 2 per thread
            for(int e=tid;e<TC*(KBX/4);e+=THR){
                const int tt=e/(KBX/4), kq=(e%(KBX/4))*4;
                float4 v={0.f,0.f,0.f,0.f};
                if(tt<tc){                       // tt<tc guard: OOB x (r15!)
                    const size_t base=((size_t)(t0+tt)*B+gr)*(size_t)NI;
                    if(kb+kq+3<NI) v=ldin4(x,base+kb+kq,fx);
                    else{
#pragma unroll
                        for(int j=0;j<4;++j)
                            ((float*)&v)[j]=(kb+kq+j<NI)?ldin(x,base+kb+kq+j,fx):0.f;
                    }
                }
                *reinterpret_cast<float4*>(&xs[tt][kq])=v;
            }
            __syncthreads();

            for(int kw=0;kw<KBX && kb+kw<NI;kw+=KW){
                // weight regs: rows n0,n1, k = kb+kw .. +KW-1 (global->VGPR)
#pragma unroll
                for(int q=0;q<KW/4;++q){
                    const int k=kb+kw+q*4;
                    const float4 a=ldw4(W1,n0,NH,NI,k,fw1);
                    const float4 b=ldw4(W1,n1,NH,NI,k,fw1);
                    wr0[q*4+0]=a.x; wr0[q*4+1]=a.y; wr0[q*4+2]=a.z; wr0[q*4+3]=a.w;
                    wr1[q*4+0]=b.x; wr1[q*4+1]=b.y; wr1[q*4+2]=b.z; wr1[q*4+3]=b.w;
                }
#pragma unroll
                for(int q=0;q<KW/4;++q){
#pragma unroll
                    for(int tt=0;tt<TC;++tt){
                        const float4 xv=*reinterpret_cast<const float4*>(&xs[tt][kw+q*4]);
                        float a=acc[tt][0];
                        a=fmaf(wr0[q*4+0],xv.x,a); a=fmaf(wr0[q*4+1],xv.y,a);
                        a=fmaf(wr0[q*4+2],xv.z,a); a=fmaf(wr0[q*4+3],xv.w,a);
                        acc[tt][0]=a;
                        float b=acc[tt][1];
                        b=fmaf(wr1[q*4+0],xv.x,b); b=fmaf(wr1[q*4+1],xv.y,b);
                        b=fmaf(wr1[q*4+2],xv.z,b); b=fmaf(wr1[q*4+3],xv.w,b);
                        acc[tt][1]=b;
                    }
                }
            }
            __syncthreads();   // xs reuse fence before next slice
        }
        // scan 1 -> spk = s1 (reset from PREVIOUS membrane; spike from NEW)
#pragma unroll
        for(int jj=0;jj<2;++jj){
            const int n=tid+THR*jj;
            if(n<NH){
#pragma unroll
                for(int tt=0;tt<TC;++tt){
                    if(tt<tc){
                        float cur=__fadd_rn(acc[tt][jj],bb1[jj]);
                        float rst=(m1[jj]>1.0f)?1.0f:0.0f;
                        m1[jj]=__fsub_rn(__fadd_rn(__fmul_rn(0.8f,m1[jj]),cur),rst);
                        spk[tt][n]=(m1[jj]>1.0f)?1.0f:0.0f;
                    }
                }
            }
        }
        __syncthreads();       // s1 visible to all

        // ====== layer 2: cur2 = s1 @ W2^T — barrier-free (spk resident) ====
#pragma unroll
        for(int tt=0;tt<TC;++tt){ acc[tt][0]=0.f; acc[tt][1]=0.f; }

        for(int kw=0;kw<NH;kw+=KW){
#pragma unroll
            for(int q=0;q<KW/4;++q){
                const int k=kw+q*4;
                const float4 a=ldw4(W2,n0,NH,NH,k,fw2);
                const float4 b=ldw4(W2,n1,NH,NH,k,fw2);
                wr0[q*4+0]=a.x; wr0[q*4+1]=a.y; wr0[q*4+2]=a.z; wr0[q*4+3]=a.w;
                wr1[q*4+0]=b.x; wr1[q*4+1]=b.y; wr1[q*4+2]=b.z; wr1[q*4+3]=b.w;
            }
#pragma unroll
            for(int q=0;q<KW/4;++q){
#pragma unroll
                for(int tt=0;tt<TC;++tt){
                    // fmaf(w, s, a), s in {0,1} == conditional add (bit-exact)
                    const float4 sv=*reinterpret_cast<const float4*>(&spk[tt][kw+q*4]);
                    float a=acc[tt][0];
                    a=fmaf(wr0[q*4+0],sv.x,a); a=fmaf(wr0[q*4+1],sv.y,a);
                    a=fmaf(wr0[q*4+2],sv.z,a); a=fmaf(wr0[q*4+3],sv.w,a);
                    acc[tt][0]=a;
                    float b=acc[tt][1];
                    b=fmaf(wr1[q*4+0],sv.x,b); b=fmaf(wr1[q*4+1],sv.y,b);
                    b=fmaf(wr1[q*4+2],sv.z,b); b=fmaf(wr1[q*4+3],sv.w,b);
                    acc[tt][1]=b;
                }
            }
        }
        __syncthreads();       // all s1 reads done before scan2 overwrites

        // scan 2 -> overwrite spk in place with s2
#pragma unroll
        for(int jj=0;jj<2;++jj){
            const int n=tid+THR*jj;
            if(n<NH){
#pragma unroll
                for(int tt=0;tt<TC;++tt){
                    if(tt<tc){
                        float cur=__fadd_rn(acc[tt][jj],bb2[jj]);
                        float rst=(m2[jj]>1.0f)?1.0f:0.0f;
                        m2[jj]=__fsub_rn(__fadd_rn(__fmul_rn(0.8f,m2[jj]),cur),rst);
                        spk[tt][n]=(m2[jj]>1.0f)?1.0f:0.0f;
                    }
                }
            }
        }
        __syncthreads();

        // ================= layer 3: parallel dots, then sequential scan ====
        if(tid<TC*NO){
            const int tt=tid/NO, o=tid%NO;
            if(tt<tc){
                float a3=0.f;
                int k=0;
                for(; k+3<NH; k+=4){
                    const float4 sv=*reinterpret_cast<const float4*>(&spk[tt][k]);
                    const float4 wv=*reinterpret_cast<const float4*>(&w3s[o][k]);
                    a3=fmaf(wv.x,sv.x,a3); a3=fmaf(wv.y,sv.y,a3);
                    a3=fmaf(wv.z,sv.z,a3); a3=fmaf(wv.w,sv.w,a3);
                }
                for(; k<NH; ++k) a3=fmaf(w3s[o][k],spk[tt][k],a3);
                d3[tt][o]=a3;
            }
        }
        __syncthreads();
        if(tid<NO){
            const int o=tid;
            for(int tt=0;tt<tc;++tt){
                float cur=__fadd_rn(d3[tt][o],bb3v);
                float rst=(m3r>1.0f)?1.0f:0.0f;
                m3r=__fsub_rn(__fadd_rn(__fmul_rn(0.8f,m3r),cur),rst);
                out[((size_t)(t0+tt)*B+gr)*(size_t)NO+o]=(m3r>1.0f)?1.0f:0.0f;
            }
        }
        __syncthreads();
    }

    // final membrane m3 (f32; harness bf16-rounds on compare)
    if(tid<NO)
        out[(size_t)T*B*NO+(size_t)gr*NO+tid]=m3r;
}

// ---------------------------------------------------------------------------
extern "C" void kernel_launch(void* const* d_in, const int* in_sizes, int n_in,
                              void* d_out, int out_size, void* d_ws, size_t ws_size,
                              hipStream_t stream)
{
    const void* x  = d_in[0];
    const void* W1 = d_in[1];
    const void* b1 = d_in[2];
    const void* W2 = d_in[3];
    const void* b2 = d_in[4];
    const void* W3 = d_in[5];
    const void* b3 = d_in[6];

    int NH = in_sizes[2];              if (NH <= 0 || NH > MAXNH) NH = 256;
    int NI = in_sizes[1] / NH;         if (NI <= 0) NI = 512;
    int NO = in_sizes[6];              if (NO <= 0 || NO > MAXNO) NO = 3;
    long TB = (long)in_sizes[0] / NI;
    long BN = (long)out_size / NO;     // T*B + B
    int B = (int)(BN - TB);            if (B <= 0) B = 1024;
    int T = (int)(TB / B);             if (T <= 0) T = 1;

    snn_f32<<<dim3(B), dim3(THR), 0, stream>>>(
        x, W1, b1, W2, b2, W3, b3, (float*)d_out, T, B, NI, NH, NO);
}

// Round 20
// 1666.413 us; speedup vs baseline: 1.0121x; 1.0121x over previous
//
#include <hip/hip_runtime.h>

// DynamicDeepSNN r19 — weights go GLOBAL->REGISTER (no wt LDS at all).
// LOCKED SEMANTICS (r12/r13/r16/r17/r18 passed, absmax 0.0 — do not change):
//   * per-output sequential-K fmaf chain, k ascending (no K-split, no MFMA)
//   * LIF: m = ((0.8f*m) + cur) - rst with separate __f*_rn roundings
//   * inputs probed bf16-or-f32 / biases zero-safe probed
//   * output f32: spk_hist (T,B,NO) then m3 (B,NO)
//   * xs staging keeps the tt<tc guard (r15 crash: OOB x read)
// r18 POST-MORTEM (1.36 ms, VALUBusy 38%): LDS unit ~2.5x oversubscribed;
// wt LDS round-trip = ~60% of LDS cycles. But each weight row is consumed by
// exactly ONE thread -> no sharing -> LDS unneeded. r19: weights load
// per-lane global->VGPR (L2-resident, same global traffic staging already
// paid); LDS keeps only truly-shared xs (broadcast) + spk. L2 layer becomes
// barrier-free; xs staged in 64-k slices (barriers /4). 12 waves/CU target.

typedef unsigned short u16;
typedef unsigned int   u32;

#define THR   128
#define TC    16
#define KBX   64     // xs staging slice (k)
#define KW    16     // weight register granularity (k)
#define MAXNH 256
#define MAXNO 4
#define SPAD  260

__device__ __forceinline__ float bf2f(u16 u){ union{u32 i;float f;}c; c.i=((u32)u)<<16; return c.f; }
__device__ __forceinline__ float ldin(const void*p,size_t e,int bf){
    return bf ? bf2f(((const u16*)p)[e]) : ((const float*)p)[e];
}
__device__ __forceinline__ float4 ldin4(const void*p,size_t e,int bf){
    if(bf){ const ushort4 u=*reinterpret_cast<const ushort4*>((const u16*)p+e);
            return float4{bf2f(u.x),bf2f(u.y),bf2f(u.z),bf2f(u.w)}; }
    return *reinterpret_cast<const float4*>((const float*)p+e);
}
// guarded 4-elem weight-row load: row n (valid<NR), k..k+3 (valid<K)
__device__ __forceinline__ float4 ldw4(const void*W,int n,int NR,int K,int k,int bf){
    float4 v={0.f,0.f,0.f,0.f};
    if(n<NR){
        if(k+3<K) v=ldin4(W,(size_t)n*K+k,bf);
        else{
#pragma unroll
            for(int j=0;j<4;++j)
                ((float*)&v)[j]=(k+j<K)?ldin(W,(size_t)n*K+k+j,bf):0.f;
        }
    }
    return v;
}

__global__ __launch_bounds__(THR,3)
void snn_f32(const void* __restrict__ x,
             const void* __restrict__ W1, const void* __restrict__ b1,
             const void* __restrict__ W2, const void* __restrict__ b2,
             const void* __restrict__ W3, const void* __restrict__ b3,
             float* __restrict__ out,
             int T,int B,int NI,int NH,int NO)
{
    __shared__ __align__(16) float xs[TC][KBX];       // 4 KB
    __shared__ __align__(16) float spk[TC][SPAD];     // 16.64 KB (s1 then s2)
    __shared__ __align__(16) float w3s[MAXNO][SPAD];  // 4.16 KB (probe red reuses)
    __shared__ float d3[TC][MAXNO];                   // 256 B
    __shared__ int   flg[8];

    const int tid=threadIdx.x, gr=blockIdx.x;         // block owns batch row gr
    int* red=(int*)&w3s[0][0];                        // probe scratch (pre-w3s)

    // ---- per-tensor dtype probes (logic identical to r12..r18) ----
    {
        const u16* ptab[7]={(const u16*)x,(const u16*)W1,(const u16*)W2,
                            (const u16*)W3,(const u16*)b1,(const u16*)b2,(const u16*)b3};
        int ntab[7];
        ntab[0]=1024; ntab[1]=1024; ntab[2]=1024;
        ntab[3]=(NO*NH>=512)?512:NO*NH;
        ntab[4]=(NH<256)?NH:256; ntab[5]=ntab[4];
        ntab[6]=(NO<MAXNO)?NO:MAXNO;
        for(int ti=0;ti<7;++ti){
            const u16* p=ptab[ti]; const int n=ntab[ti];
            int cnt=0,nz=0;
            for(int i=tid;i<n;i+=THR){ u16 v=p[i]; if(v)++nz;
                float a=fabsf(bf2f(v)); if(a>1e-3f&&a<64.f)++cnt; }
            red[tid]=cnt; __syncthreads();
            for(int s=THR/2;s>0;s>>=1){ if(tid<s) red[tid]+=red[tid+s]; __syncthreads(); }
            int ca=red[0]; __syncthreads();
            red[tid]=nz; __syncthreads();
            for(int s=THR/2;s>0;s>>=1){ if(tid<s) red[tid]+=red[tid+s]; __syncthreads(); }
            if(tid==0){ int na=red[0]; flg[ti]=(na==0)?-1:((ca*5>n*4)?1:0); }
            __syncthreads();
        }
    }
    const int fx =__builtin_amdgcn_readfirstlane(flg[0]==1);
    const int fw1=__builtin_amdgcn_readfirstlane(flg[1]==1);
    const int fw2=__builtin_amdgcn_readfirstlane(flg[2]==1);
    const int fw3=__builtin_amdgcn_readfirstlane(flg[3]==1);

    // this thread's two neurons
    const int n0=tid, n1=tid+THR;

    float bb1[2]={0.f,0.f}, bb2[2]={0.f,0.f};
#pragma unroll
    for(int jj=0;jj<2;++jj){
        const int n=tid+THR*jj;
        if(n<NH){ if(flg[4]>=0) bb1[jj]=ldin(b1,(size_t)n,flg[4]==1);
                  if(flg[5]>=0) bb2[jj]=ldin(b2,(size_t)n,flg[5]==1); }
    }
    float bb3v=0.f;
    if(tid<NO && flg[6]>=0) bb3v=ldin(b3,(size_t)tid,flg[6]==1);
    __syncthreads();   // probes done before w3s overwrites red

    // stage W3 once; zero spike buffer (pad cols stay 0 forever)
    for(int e=tid;e<MAXNO*MAXNH;e+=THR){
        int o=e>>8,k=e&255;
        w3s[o][k]=(o<NO&&k<NH)? ldin(W3,(size_t)o*NH+k,fw3):0.f;
    }
    for(int e=tid;e<TC*SPAD;e+=THR) (&spk[0][0])[e]=0.f;
    __syncthreads();

    float m1[2]={0.f,0.f}, m2[2]={0.f,0.f}, m3r=0.f;
    float acc[TC][2];
    float wr0[KW], wr1[KW];

    for(int t0=0;t0<T;t0+=TC){
        const int tc=(T-t0<TC)?(T-t0):TC;

        // ================= layer 1: cur1 = x @ W1^T (sequential k) =========
#pragma unroll
        for(int tt=0;tt<TC;++tt){ acc[tt][0]=0.f; acc[tt][1]=0.f; }

        for(int kb=0;kb<NI;kb+=KBX){
            // stage xs slice kb..kb+63: TC*(KBX/4)=256 quads, 2 per thread
            for(int e=tid;e<TC*(KBX/4);e+=THR){
                const int tt=e/(KBX/4), kq=(e%(KBX/4))*4;
                float4 v={0.f,0.f,0.f,0.f};
                if(tt<tc){                       // tt<tc guard: OOB x (r15!)
                    const size_t base=((size_t)(t0+tt)*B+gr)*(size_t)NI;
                    if(kb+kq+3<NI) v=ldin4(x,base+kb+kq,fx);
                    else{
#pragma unroll
                        for(int j=0;j<4;++j)
                            ((float*)&v)[j]=(kb+kq+j<NI)?ldin(x,base+kb+kq+j,fx):0.f;
                    }
                }
                *reinterpret_cast<float4*>(&xs[tt][kq])=v;
            }
            __syncthreads();

            for(int kw=0;kw<KBX && kb+kw<NI;kw+=KW){
                // weight regs: rows n0,n1, k = kb+kw .. +KW-1 (global->VGPR)
#pragma unroll
                for(int q=0;q<KW/4;++q){
                    const int k=kb+kw+q*4;
                    const float4 a=ldw4(W1,n0,NH,NI,k,fw1);
                    const float4 b=ldw4(W1,n1,NH,NI,k,fw1);
                    wr0[q*4+0]=a.x; wr0[q*4+1]=a.y; wr0[q*4+2]=a.z; wr0[q*4+3]=a.w;
                    wr1[q*4+0]=b.x; wr1[q*4+1]=b.y; wr1[q*4+2]=b.z; wr1[q*4+3]=b.w;
                }
#pragma unroll
                for(int q=0;q<KW/4;++q){
#pragma unroll
                    for(int tt=0;tt<TC;++tt){
                        const float4 xv=*reinterpret_cast<const float4*>(&xs[tt][kw+q*4]);
                        float a=acc[tt][0];
                        a=fmaf(wr0[q*4+0],xv.x,a); a=fmaf(wr0[q*4+1],xv.y,a);
                        a=fmaf(wr0[q*4+2],xv.z,a); a=fmaf(wr0[q*4+3],xv.w,a);
                        acc[tt][0]=a;
                        float b=acc[tt][1];
                        b=fmaf(wr1[q*4+0],xv.x,b); b=fmaf(wr1[q*4+1],xv.y,b);
                        b=fmaf(wr1[q*4+2],xv.z,b); b=fmaf(wr1[q*4+3],xv.w,b);
                        acc[tt][1]=b;
                    }
                }
            }
            __syncthreads();   // xs reuse fence before next slice
        }
        // scan 1 -> spk = s1 (reset from PREVIOUS membrane; spike from NEW)
#pragma unroll
        for(int jj=0;jj<2;++jj){
            const int n=tid+THR*jj;
            if(n<NH){
#pragma unroll
                for(int tt=0;tt<TC;++tt){
                    if(tt<tc){
                        float cur=__fadd_rn(acc[tt][jj],bb1[jj]);
                        float rst=(m1[jj]>1.0f)?1.0f:0.0f;
                        m1[jj]=__fsub_rn(__fadd_rn(__fmul_rn(0.8f,m1[jj]),cur),rst);
                        spk[tt][n]=(m1[jj]>1.0f)?1.0f:0.0f;
                    }
                }
            }
        }
        __syncthreads();       // s1 visible to all

        // ====== layer 2: cur2 = s1 @ W2^T — barrier-free (spk resident) ====
#pragma unroll
        for(int tt=0;tt<TC;++tt){ acc[tt][0]=0.f; acc[tt][1]=0.f; }

        for(int kw=0;kw<NH;kw+=KW){
#pragma unroll
            for(int q=0;q<KW/4;++q){
                const int k=kw+q*4;
                const float4 a=ldw4(W2,n0,NH,NH,k,fw2);
                const float4 b=ldw4(W2,n1,NH,NH,k,fw2);
                wr0[q*4+0]=a.x; wr0[q*4+1]=a.y; wr0[q*4+2]=a.z; wr0[q*4+3]=a.w;
                wr1[q*4+0]=b.x; wr1[q*4+1]=b.y; wr1[q*4+2]=b.z; wr1[q*4+3]=b.w;
            }
#pragma unroll
            for(int q=0;q<KW/4;++q){
#pragma unroll
                for(int tt=0;tt<TC;++tt){
                    // fmaf(w, s, a), s in {0,1} == conditional add (bit-exact)
                    const float4 sv=*reinterpret_cast<const float4*>(&spk[tt][kw+q*4]);
                    float a=acc[tt][0];
                    a=fmaf(wr0[q*4+0],sv.x,a); a=fmaf(wr0[q*4+1],sv.y,a);
                    a=fmaf(wr0[q*4+2],sv.z,a); a=fmaf(wr0[q*4+3],sv.w,a);
                    acc[tt][0]=a;
                    float b=acc[tt][1];
                    b=fmaf(wr1[q*4+0],sv.x,b); b=fmaf(wr1[q*4+1],sv.y,b);
                    b=fmaf(wr1[q*4+2],sv.z,b); b=fmaf(wr1[q*4+3],sv.w,b);
                    acc[tt][1]=b;
                }
            }
        }
        __syncthreads();       // all s1 reads done before scan2 overwrites

        // scan 2 -> overwrite spk in place with s2
#pragma unroll
        for(int jj=0;jj<2;++jj){
            const int n=tid+THR*jj;
            if(n<NH){
#pragma unroll
                for(int tt=0;tt<TC;++tt){
                    if(tt<tc){
                        float cur=__fadd_rn(acc[tt][jj],bb2[jj]);
                        float rst=(m2[jj]>1.0f)?1.0f:0.0f;
                        m2[jj]=__fsub_rn(__fadd_rn(__fmul_rn(0.8f,m2[jj]),cur),rst);
                        spk[tt][n]=(m2[jj]>1.0f)?1.0f:0.0f;
                    }
                }
            }
        }
        __syncthreads();

        // ================= layer 3: parallel dots, then sequential scan ====
        if(tid<TC*NO){
            const int tt=tid/NO, o=tid%NO;
            if(tt<tc){
                float a3=0.f;
                int k=0;
                for(; k+3<NH; k+=4){
                    const float4 sv=*reinterpret_cast<const float4*>(&spk[tt][k]);
                    const float4 wv=*reinterpret_cast<const float4*>(&w3s[o][k]);
                    a3=fmaf(wv.x,sv.x,a3); a3=fmaf(wv.y,sv.y,a3);
                    a3=fmaf(wv.z,sv.z,a3); a3=fmaf(wv.w,sv.w,a3);
                }
                for(; k<NH; ++k) a3=fmaf(w3s[o][k],spk[tt][k],a3);
                d3[tt][o]=a3;
            }
        }
        __syncthreads();
        if(tid<NO){
            const int o=tid;
            for(int tt=0;tt<tc;++tt){
                float cur=__fadd_rn(d3[tt][o],bb3v);
                float rst=(m3r>1.0f)?1.0f:0.0f;
                m3r=__fsub_rn(__fadd_rn(__fmul_rn(0.8f,m3r),cur),rst);
                out[((size_t)(t0+tt)*B+gr)*(size_t)NO+o]=(m3r>1.0f)?1.0f:0.0f;
            }
        }
        __syncthreads();
    }

    // final membrane m3 (f32; harness bf16-rounds on compare)
    if(tid<NO)
        out[(size_t)T*B*NO+(size_t)gr*NO+tid]=m3r;
}

// ---------------------------------------------------------------------------
extern "C" void kernel_launch(void* const* d_in, const int* in_sizes, int n_in,
                              void* d_out, int out_size, void* d_ws, size_t ws_size,
                              hipStream_t stream)
{
    const void* x  = d_in[0];
    const void* W1 = d_in[1];
    const void* b1 = d_in[2];
    const void* W2 = d_in[3];
    const void* b2 = d_in[4];
    const void* W3 = d_in[5];
    const void* b3 = d_in[6];

    int NH = in_sizes[2];              if (NH <= 0 || NH > MAXNH) NH = 256;
    int NI = in_sizes[1] / NH;         if (NI <= 0) NI = 512;
    int NO = in_sizes[6];              if (NO <= 0 || NO > MAXNO) NO = 3;
    long TB = (long)in_sizes[0] / NI;
    long BN = (long)out_size / NO;     // T*B + B
    int B = (int)(BN - TB);            if (B <= 0) B = 1024;
    int T = (int)(TB / B);             if (T <= 0) T = 1;

    snn_f32<<<dim3(B), dim3(THR), 0, stream>>>(
        x, W1, b1, W2, b2, W3, b3, (float*)d_out, T, B, NI, NH, NO);
}